// Round 6
// baseline (711.035 us; speedup 1.0000x reference)
//
#include <hip/hip_runtime.h>

// GRU: B=256, T=1000, I=64, H=128.
// Round-1/5 structure (known-good): 1 batch row/block, 512 threads,
// tid = j*4+ks (j=hidden unit, ks=k-slice of 4). Per-thread weights:
// 3 gate-rows x (32 W_hh + 16 W_ih) = 144 floats.
//
// Round-6 single change: __attribute__((amdgpu_waves_per_eu(2,2))).
// Evidence (r1/r4/r5): allocator pins arch VGPRs at ~104 and demotes the
// rest of the weight arrays to AGPRs; each AGPR use costs a v_accvgpr_read
// (measured ~413 VALU inst/wave/step vs ~220 useful). launch_bounds' 2nd
// arg only sets the occupancy FLOOR; waves_per_eu(2,2) also caps the
// allocator's occupancy TARGET at 2 waves/EU -> 256-reg arch budget ->
// weights stay in arch VGPRs, no move traffic.

#define Bc 256
#define Tc 1000
#define Ic 64
#define Hc 128

#define HSKEW(k) ((k) + (((k) >> 5) << 2))
#define HBUF_W (Hc + 16)

__device__ __forceinline__ float fast_sigmoid(float x) {
    return __builtin_amdgcn_rcpf(1.0f + __expf(-x));
}
__device__ __forceinline__ float fast_tanh(float x) {
    return 1.0f - 2.0f * __builtin_amdgcn_rcpf(__expf(2.0f * x) + 1.0f);
}
// add value from lane^1 within the quad: DPP quad_perm [1,0,3,2]
__device__ __forceinline__ float dpp_xor1_add(float x) {
    int y = __builtin_amdgcn_update_dpp(0, __float_as_int(x), 0xB1, 0xF, 0xF, true);
    return x + __int_as_float(y);
}
// add value from lane^2 within the quad: DPP quad_perm [2,3,0,1]
__device__ __forceinline__ float dpp_xor2_add(float x) {
    int y = __builtin_amdgcn_update_dpp(0, __float_as_int(x), 0x4E, 0xF, 0xF, true);
    return x + __int_as_float(y);
}

__global__ __launch_bounds__(512)
__attribute__((amdgpu_waves_per_eu(2, 2)))
void gru_scan_kernel(
    const float* __restrict__ input,   // [B][T][I]
    const float* __restrict__ W_ih,    // [3H][I]
    const float* __restrict__ W_hh,    // [3H][H]
    const float* __restrict__ b_ih,    // [3H]
    const float* __restrict__ b_hh,    // [3H]
    float* __restrict__ out)           // states [B][T][H] then hT [B][H]
{
    const int b   = blockIdx.x;
    const int tid = threadIdx.x;
    const int j   = tid >> 2;
    const int ks  = tid & 3;

    __shared__ float hbuf[2][HBUF_W];
    __shared__ float ibuf[2][Ic];

    // ---- persistent weights in registers ----
    float wr[32], wz[32], wn[32];
    {
        const float* pr = W_hh + (size_t)j * Hc + ks * 32;
        const float* pz = W_hh + (size_t)(Hc + j) * Hc + ks * 32;
        const float* pn = W_hh + (size_t)(2 * Hc + j) * Hc + ks * 32;
#pragma unroll
        for (int q = 0; q < 8; ++q) {
            *reinterpret_cast<float4*>(&wr[q * 4]) = reinterpret_cast<const float4*>(pr)[q];
            *reinterpret_cast<float4*>(&wz[q * 4]) = reinterpret_cast<const float4*>(pz)[q];
            *reinterpret_cast<float4*>(&wn[q * 4]) = reinterpret_cast<const float4*>(pn)[q];
        }
    }
    float ur[16], uz[16], un[16];
    {
        const float* pr = W_ih + (size_t)j * Ic + ks * 16;
        const float* pz = W_ih + (size_t)(Hc + j) * Ic + ks * 16;
        const float* pn = W_ih + (size_t)(2 * Hc + j) * Ic + ks * 16;
#pragma unroll
        for (int q = 0; q < 4; ++q) {
            *reinterpret_cast<float4*>(&ur[q * 4]) = reinterpret_cast<const float4*>(pr)[q];
            *reinterpret_cast<float4*>(&uz[q * 4]) = reinterpret_cast<const float4*>(pz)[q];
            *reinterpret_cast<float4*>(&un[q * 4]) = reinterpret_cast<const float4*>(pn)[q];
        }
    }
    // biases pre-scaled by 1/4: accumulator-init form (4-lane reduce restores 1x)
    const float br4  = 0.25f * (b_ih[j] + b_hh[j]);
    const float bz4  = 0.25f * (b_ih[Hc + j] + b_hh[Hc + j]);
    const float bnx4 = 0.25f * b_ih[2 * Hc + j];
    const float bnh4 = 0.25f * b_hh[2 * Hc + j];

    const float* inp_b    = input + (size_t)b * Tc * Ic;
    float*       states_b = out + (size_t)b * Tc * Hc;
    float*       hT_out   = out + (size_t)Bc * Tc * Hc + (size_t)b * Hc;

    // ---- prologue: h0 = 0, stage input rows 0 and 1 ----
    float in_t1 = 0.0f;
    if (tid < Ic) {
        ibuf[0][tid] = inp_b[tid];
        in_t1        = inp_b[Ic + tid];  // row 1
    }
    if (tid < HBUF_W) hbuf[0][tid] = 0.0f;
    __syncthreads();

    for (int t = 0; t < Tc; ++t) {
        const int rb = t & 1;
        const int wb = rb ^ 1;

        // prefetch input row t+2
        float in_t2 = 0.0f;
        if (tid < Ic) {
            const int tn = (t + 2 < Tc) ? (t + 2) : (Tc - 1);
            in_t2 = inp_b[(size_t)tn * Ic + tid];
        }

        const float h_old = hbuf[rb][HSKEW(j)];

        float ar0 = br4,  ar1 = 0.f;   // r gate (x+h combined)
        float az0 = bz4,  az1 = 0.f;   // z gate (x+h combined)
        float ah0 = bnh4, ah1 = 0.f;   // n gate, hidden part
        float ax0 = bnx4, ax1 = 0.f;   // n gate, input part

        // hidden dot: k in [32ks, 32ks+32)
        const float* hb = &hbuf[rb][HSKEW(ks * 32)];
#pragma unroll
        for (int q = 0; q < 8; ++q) {
            const float4 hv = *reinterpret_cast<const float4*>(hb + q * 4);
            ar0 = fmaf(hv.x, wr[4 * q + 0], ar0);
            az0 = fmaf(hv.x, wz[4 * q + 0], az0);
            ah0 = fmaf(hv.x, wn[4 * q + 0], ah0);
            ar1 = fmaf(hv.y, wr[4 * q + 1], ar1);
            az1 = fmaf(hv.y, wz[4 * q + 1], az1);
            ah1 = fmaf(hv.y, wn[4 * q + 1], ah1);
            ar0 = fmaf(hv.z, wr[4 * q + 2], ar0);
            az0 = fmaf(hv.z, wz[4 * q + 2], az0);
            ah0 = fmaf(hv.z, wn[4 * q + 2], ah0);
            ar1 = fmaf(hv.w, wr[4 * q + 3], ar1);
            az1 = fmaf(hv.w, wz[4 * q + 3], az1);
            ah1 = fmaf(hv.w, wn[4 * q + 3], ah1);
        }
        // input dot: k' in [16ks, 16ks+16)
        const float* ib = &ibuf[rb][ks * 16];
#pragma unroll
        for (int q = 0; q < 4; ++q) {
            const float4 iv = *reinterpret_cast<const float4*>(ib + q * 4);
            ar0 = fmaf(iv.x, ur[4 * q + 0], ar0);
            az0 = fmaf(iv.x, uz[4 * q + 0], az0);
            ax0 = fmaf(iv.x, un[4 * q + 0], ax0);
            ar1 = fmaf(iv.y, ur[4 * q + 1], ar1);
            az1 = fmaf(iv.y, uz[4 * q + 1], az1);
            ax1 = fmaf(iv.y, un[4 * q + 1], ax1);
            ar0 = fmaf(iv.z, ur[4 * q + 2], ar0);
            az0 = fmaf(iv.z, uz[4 * q + 2], az0);
            ax0 = fmaf(iv.z, un[4 * q + 2], ax0);
            ar1 = fmaf(iv.w, ur[4 * q + 3], ar1);
            az1 = fmaf(iv.w, uz[4 * q + 3], az1);
            ax1 = fmaf(iv.w, un[4 * q + 3], ax1);
        }

        // quad reduce: 2 DPP levels, pure VALU
        float ar = dpp_xor2_add(dpp_xor1_add(ar0 + ar1));
        float az = dpp_xor2_add(dpp_xor1_add(az0 + az1));
        float ah = dpp_xor2_add(dpp_xor1_add(ah0 + ah1));
        float ax = dpp_xor2_add(dpp_xor1_add(ax0 + ax1));

        // gates (replicated across the quad — cheap, keeps epilogue local)
        const float r    = fast_sigmoid(ar);
        const float z    = fast_sigmoid(az);
        const float n    = fast_tanh(ax + r * ah);
        const float hnew = n + z * (h_old - n);

        // spread epilogue stores across quad lanes
        if (ks == 0) hbuf[wb][HSKEW(j)] = hnew;
        else if (ks == 1) states_b[(size_t)t * Hc + j] = hnew;
        else if (ks == 2) { if (t == Tc - 1) hT_out[j] = hnew; }
        if (tid < Ic) {
            ibuf[wb][tid] = in_t1;
            in_t1 = in_t2;
        }
        __syncthreads();
    }
}

extern "C" void kernel_launch(void* const* d_in, const int* in_sizes, int n_in,
                              void* d_out, int out_size, void* d_ws, size_t ws_size,
                              hipStream_t stream) {
    const float* input = (const float*)d_in[0];
    const float* W_ih  = (const float*)d_in[1];
    const float* W_hh  = (const float*)d_in[2];
    const float* b_ih  = (const float*)d_in[3];
    const float* b_hh  = (const float*)d_in[4];
    float* out = (float*)d_out;
    (void)in_sizes; (void)n_in; (void)d_ws; (void)ws_size; (void)out_size;

    gru_scan_kernel<<<Bc, 512, 0, stream>>>(input, W_ih, W_hh, b_ih, b_hh, out);
}